// Round 2
// baseline (646.240 us; speedup 1.0000x reference)
//
#include <hip/hip_runtime.h>

// Correlation cost volume: B=16, C=256, H=W=96, k=1, d=4, s1=s2=1.
// out[b,(dy+4)*9+(dx+4),y,x] = (1/256) * sum_c x1[b,c,y,x] * x2[b,c,y+dy,x+dx]
// Thread = (row r, dy, 8-px strip) -> 72 accs. Block tile = 4 rows x 48 cols.
// All LDS accesses are ds_read_b128/ds_write_b128 (pitches 52/60, 16B aligned).
// Grid = 24 row-tiles x 2 col-tiles x 16 batch = 768 blocks = 3/CU exactly.

namespace {
constexpr int Bsz = 16, Cch = 256, Hh = 96, Ww = 96, HW = Hh * Ww;
constexpr int Dd = 4, ND = 9;               // 2*d+1
constexpr int TH = 4;                       // rows per tile
constexpr int TW = 48;                      // cols per tile
constexpr int PX = 8;                       // pixels per thread
constexpr int NS = TW / PX;                 // 6 strips
constexpr int CC = 4;                       // channels per LDS stage
constexpr int NT = TH * ND * NS;            // 216 threads
constexpr int X2R = TH + 2 * Dd;            // 12 padded rows
constexpr int X1P = 52;                     // x1 LDS pitch (16B-aligned, bank-spread)
constexpr int X2P = 60;                     // x2 LDS pitch (16B-aligned, quad-spread)
constexpr int X1CH = TH * X1P;              // 208 floats / channel
constexpr int X2CH = X2R * X2P;             // 720 floats / channel
constexpr int X1SZ = CC * X1CH;             // 832
constexpr int X2SZ = CC * X2CH;             // 2880  (total LDS = 14.8 KB)
constexpr int X1G = TW / 4;                 // 12 f4 groups per x1 row
constexpr int X2G = (TW + 2 * Dd) / 4;      // 14 f4 groups per padded x2 row
constexpr int N_X1 = CC * TH * X1G;         // 192 staging items
constexpr int N_X2 = CC * X2R * X2G;        // 672
constexpr int NI = N_X1 + N_X2;             // 864 == 4 * NT exactly
}

__global__ __launch_bounds__(NT, 3)
void corr81(const float* __restrict__ x1, const float* __restrict__ x2,
            float* __restrict__ out) {
  __shared__ float lds[X1SZ + X2SZ];

  const int t   = threadIdx.x;
  const int y0  = blockIdx.x * TH;
  const int x0t = blockIdx.y * TW;
  const int b   = blockIdx.z;

  const int r   = t / (ND * NS);            // 0..3
  const int rem = t % (ND * NS);
  const int dyi = rem / NS;                 // 0..8 (dy+4)
  const int s   = rem % NS;                 // 0..5

  const float* __restrict__ x1b = x1 + (size_t)b * Cch * HW;
  const float* __restrict__ x2b = x2 + (size_t)b * Cch * HW;

  // ---- staging descriptors: exactly 4 float4 items per thread ----
  const float* gp[4];
  int  loff[4];
  bool zero[4];
#pragma unroll
  for (int j = 0; j < 4; ++j) {
    int i = t + j * NT;
    if (i < N_X1) {
      int c  = i / (TH * X1G);
      int rm = i % (TH * X1G);
      int ry = rm / X1G, g = rm % X1G;      // always in-bounds
      gp[j]   = x1b + c * HW + (y0 + ry) * Ww + x0t + 4 * g;
      loff[j] = c * X1CH + ry * X1P + 4 * g;
      zero[j] = false;
    } else {
      int m  = i - N_X1;
      int c  = m / (X2R * X2G);
      int rm = m % (X2R * X2G);
      int ry = rm / X2G, g = rm % X2G;
      int gy = y0 + ry - Dd;
      int gx = x0t + 4 * g - Dd;            // multiple of 4 -> group-granular validity
      bool z = (gy < 0) | (gy >= Hh) | (gx < 0) | (gx > Ww - 4);
      gp[j]   = z ? x2b : (x2b + c * HW + gy * Ww + gx);
      loff[j] = X1SZ + c * X2CH + ry * X2P + 4 * g;
      zero[j] = z;
    }
  }

  float acc[ND][PX];
#pragma unroll
  for (int i = 0; i < ND; ++i)
#pragma unroll
    for (int j = 0; j < PX; ++j) acc[i][j] = 0.f;

  // ---- prefetch stage 0 ----
  float4 v[4];
#pragma unroll
  for (int j = 0; j < 4; ++j)
    v[j] = zero[j] ? make_float4(0.f, 0.f, 0.f, 0.f) : *(const float4*)gp[j];

  for (int c0 = 0; c0 < Cch; c0 += CC) {
    __syncthreads();                        // previous compute done with LDS
#pragma unroll
    for (int j = 0; j < 4; ++j)
      *(float4*)(lds + loff[j]) = v[j];     // all ds_write_b128
    __syncthreads();
    if (c0 + CC < Cch) {                    // issue next stage before compute
#pragma unroll
      for (int j = 0; j < 4; ++j) {
        gp[j] += CC * HW;
        v[j] = zero[j] ? make_float4(0.f, 0.f, 0.f, 0.f) : *(const float4*)gp[j];
      }
    }
    // ---- compute: per channel 2+4 ds_read_b128, 72 FMAs per thread ----
#pragma unroll
    for (int cc = 0; cc < CC; ++cc) {
      const float* ap = lds + cc * X1CH + r * X1P + PX * s;
      float a[PX];
      *(float4*)(a)     = *(const float4*)(ap);
      *(float4*)(a + 4) = *(const float4*)(ap + 4);
      const float* bp = lds + X1SZ + cc * X2CH + (r + dyi) * X2P + PX * s;
      float bb[16];
#pragma unroll
      for (int q = 0; q < 4; ++q)
        *(float4*)(bb + 4 * q) = *(const float4*)(bp + 4 * q);
#pragma unroll
      for (int dx = 0; dx < ND; ++dx)
#pragma unroll
        for (int px = 0; px < PX; ++px)
          acc[dx][px] += a[px] * bb[px + dx];
    }
  }

  // ---- epilogue ----
  const float nrm = 1.0f / (float)Cch;
  float* ob = out + ((size_t)b * (ND * ND) + (size_t)dyi * ND) * HW
                  + (size_t)(y0 + r) * Ww + x0t + PX * s;
#pragma unroll
  for (int dx = 0; dx < ND; ++dx) {
    float4 w0, w1;
    w0.x = acc[dx][0] * nrm; w0.y = acc[dx][1] * nrm;
    w0.z = acc[dx][2] * nrm; w0.w = acc[dx][3] * nrm;
    w1.x = acc[dx][4] * nrm; w1.y = acc[dx][5] * nrm;
    w1.z = acc[dx][6] * nrm; w1.w = acc[dx][7] * nrm;
    *(float4*)(ob + (size_t)dx * HW)     = w0;
    *(float4*)(ob + (size_t)dx * HW + 4) = w1;
  }
}

extern "C" void kernel_launch(void* const* d_in, const int* in_sizes, int n_in,
                              void* d_out, int out_size, void* d_ws, size_t ws_size,
                              hipStream_t stream) {
  const float* x1 = (const float*)d_in[0];
  const float* x2 = (const float*)d_in[1];
  float* out = (float*)d_out;
  dim3 grid(Hh / TH, Ww / TW, Bsz);  // 24 x 2 x 16 = 768 blocks
  dim3 block(NT);                    // 216 threads
  hipLaunchKernelGGL(corr81, grid, block, 0, stream, x1, x2, out);
}